// Round 2
// baseline (2703.704 us; speedup 1.0000x reference)
//
#include <hip/hip_runtime.h>
#include <hip/hip_bf16.h>

#define N_NODES 200000
#define N_EDGES 800000
#define N_GRAPHS 512

typedef __hip_bfloat16 bf16;

__device__ inline float toF(float v) { return v; }
__device__ inline float toF(bf16 v) { return __bfloat162float(v); }

// ---------------- CSR build ----------------

__global__ __launch_bounds__(256) void count_edges(const int* __restrict__ dst, int E,
                                                   int* __restrict__ cnt) {
    int e = blockIdx.x * 256 + threadIdx.x;
    if (e < E) atomicAdd(&cnt[dst[e]], 1);
}

__global__ __launch_bounds__(512) void block_reduce(const int* __restrict__ in, int n,
                                                    int* __restrict__ bsum) {
    __shared__ int s[512];
    int i = blockIdx.x * 512 + threadIdx.x;
    s[threadIdx.x] = (i < n) ? in[i] : 0;
    __syncthreads();
    for (int off = 256; off; off >>= 1) {
        if (threadIdx.x < off) s[threadIdx.x] += s[threadIdx.x + off];
        __syncthreads();
    }
    if (threadIdx.x == 0) bsum[blockIdx.x] = s[0];
}

__global__ __launch_bounds__(512) void scan_bsums(int* bsum, int nb) {
    __shared__ int buf[2][512];
    int t = threadIdx.x;
    int v = (t < nb) ? bsum[t] : 0;
    buf[0][t] = v;
    __syncthreads();
    int src = 0;
    for (int off = 1; off < 512; off <<= 1) {
        int x = buf[src][t];
        if (t >= off) x += buf[src][t - off];
        buf[src ^ 1][t] = x;
        src ^= 1;
        __syncthreads();
    }
    if (t < nb) bsum[t] = buf[src][t] - v;  // exclusive
}

__global__ __launch_bounds__(512) void block_scan_write(const int* __restrict__ cnt,
                                                        const int* __restrict__ bsum, int n,
                                                        int* __restrict__ rowptr) {
    __shared__ int buf[2][512];
    int t = threadIdx.x;
    int i = blockIdx.x * 512 + t;
    int v = (i < n) ? cnt[i] : 0;
    buf[0][t] = v;
    __syncthreads();
    int src = 0;
    for (int off = 1; off < 512; off <<= 1) {
        int x = buf[src][t];
        if (t >= off) x += buf[src][t - off];
        buf[src ^ 1][t] = x;
        src ^= 1;
        __syncthreads();
    }
    int incl = buf[src][t];
    int base = bsum[blockIdx.x];
    if (i < n) rowptr[i] = base + incl - v;
    if (i == n - 1) rowptr[n] = base + incl;
}

__global__ __launch_bounds__(256) void fill_csr(const int* __restrict__ src,
                                                const int* __restrict__ dst, int E,
                                                const int* __restrict__ rowptr,
                                                int* __restrict__ cur, int* __restrict__ col) {
    int e = blockIdx.x * 256 + threadIdx.x;
    if (e < E) {
        int d = dst[e];
        int p = atomicAdd(&cur[d], 1);
        col[rowptr[d] + p] = src[e];
    }
}

__global__ __launch_bounds__(256) void compute_dinv(const int* __restrict__ rowptr, int n,
                                                    float* __restrict__ dinv) {
    int v = blockIdx.x * 256 + threadIdx.x;
    if (v < n) {
        int deg = rowptr[v + 1] - rowptr[v] + 1;  // +1 self loop
        dinv[v] = rsqrtf((float)deg);
    }
}

// ---------------- GCN aggregation: out[v] = dinv[v]*(dinv[v]*X[v] + sum dinv[u]*X[u]) ------

template <int F, typename TIN>
__global__ __launch_bounds__(256) void aggregate(const TIN* __restrict__ X,
                                                 const float* __restrict__ dinv,
                                                 const int* __restrict__ rowptr,
                                                 const int* __restrict__ col,
                                                 bf16* __restrict__ out) {
    int v = blockIdx.x;
    int f = threadIdx.x;
    int r0 = rowptr[v], r1 = rowptr[v + 1];
    float dv = dinv[v];
    float acc = 0.f;
    if (f < F) acc = toF(X[(size_t)v * F + f]) * dv;
    for (int e = r0; e < r1; ++e) {
        int u = col[e];
        float du = dinv[u];
        if (f < F) acc += toF(X[(size_t)u * F + f]) * du;
    }
    if (f < F) out[(size_t)v * F + f] = __float2bfloat16(acc * dv);
}

// ------- GEMM: C = act(A[M,K] @ B[K,N] + bias[N]); optional fused relu+segment_max -------

template <typename AT, typename CT, int ACT, int SEGMAX>
__global__ __launch_bounds__(256) void gemm_rrr(const AT* __restrict__ A,
                                                const float* __restrict__ B,
                                                const float* __restrict__ bias,
                                                CT* __restrict__ C, int M, int N, int K, int ldc,
                                                const int* __restrict__ batch,
                                                unsigned int* __restrict__ g3bits) {
    __shared__ float As[16][68];
    __shared__ float Bs[16][68];
    __shared__ float red[16][64];
    int tid = threadIdx.x;
    int bx = blockIdx.x, by = blockIdx.y;
    int tx = tid & 15, ty = tid >> 4;
    int m0 = by * 64 + ty * 4;
    int n0 = bx * 64 + tx * 4;
    float acc[4][4] = {};
    for (int kt = 0; kt < K; kt += 16) {
#pragma unroll
        for (int l = 0; l < 4; l++) {
            int idx = tid + l * 256;
            int m_l = idx >> 4, k_l = idx & 15;
            int gm = by * 64 + m_l, gk = kt + k_l;
            As[k_l][m_l] = (gm < M && gk < K) ? toF(A[(size_t)gm * K + gk]) : 0.f;
        }
#pragma unroll
        for (int l = 0; l < 4; l++) {
            int idx = tid + l * 256;
            int k_l = idx >> 6, n_l = idx & 63;
            int gk = kt + k_l, gn = bx * 64 + n_l;
            Bs[k_l][n_l] = (gk < K && gn < N) ? B[(size_t)gk * N + gn] : 0.f;
        }
        __syncthreads();
#pragma unroll
        for (int k = 0; k < 16; k++) {
            float a0 = As[k][ty * 4 + 0], a1 = As[k][ty * 4 + 1];
            float a2 = As[k][ty * 4 + 2], a3 = As[k][ty * 4 + 3];
            float b0 = Bs[k][tx * 4 + 0], b1 = Bs[k][tx * 4 + 1];
            float b2 = Bs[k][tx * 4 + 2], b3 = Bs[k][tx * 4 + 3];
            acc[0][0] += a0 * b0; acc[0][1] += a0 * b1; acc[0][2] += a0 * b2; acc[0][3] += a0 * b3;
            acc[1][0] += a1 * b0; acc[1][1] += a1 * b1; acc[1][2] += a1 * b2; acc[1][3] += a1 * b3;
            acc[2][0] += a2 * b0; acc[2][1] += a2 * b1; acc[2][2] += a2 * b2; acc[2][3] += a2 * b3;
            acc[3][0] += a3 * b0; acc[3][1] += a3 * b1; acc[3][2] += a3 * b2; acc[3][3] += a3 * b3;
        }
        __syncthreads();
    }

    if (SEGMAX) {
        // relu + per-graph max. batch sorted -> block rows usually one graph.
        int mblk = by * 64;
        bool uni = (mblk + 63 < M) && (batch[mblk] == batch[mblk + 63]);
        if (uni) {
#pragma unroll
            for (int j = 0; j < 4; j++) {
                int gn = n0 + j;
                float v = 0.f;
                if (gn < N) {
                    float bj = bias[gn];
#pragma unroll
                    for (int i = 0; i < 4; i++) v = fmaxf(v, acc[i][j] + bj);
                }
                red[ty][tx * 4 + j] = v;
            }
            __syncthreads();
            if (tid < 64) {
                int gn = bx * 64 + tid;
                if (gn < N) {
                    float m = red[0][tid];
#pragma unroll
                    for (int r = 1; r < 16; r++) m = fmaxf(m, red[r][tid]);
                    atomicMax(&g3bits[(size_t)batch[mblk] * N + gn], __float_as_uint(m));
                }
            }
        } else {
#pragma unroll
            for (int j = 0; j < 4; j++) {
                int gn = n0 + j;
                if (gn < N) {
                    float bj = bias[gn];
#pragma unroll
                    for (int i = 0; i < 4; i++) {
                        int gm = m0 + i;
                        if (gm < M) {
                            float v = fmaxf(acc[i][j] + bj, 0.f);
                            atomicMax(&g3bits[(size_t)batch[gm] * N + gn], __float_as_uint(v));
                        }
                    }
                }
            }
        }
        return;
    }

#pragma unroll
    for (int i = 0; i < 4; i++) {
#pragma unroll
        for (int j = 0; j < 4; j++) {
            int gm = m0 + i, gn = n0 + j;
            if (gm < M && gn < N) {
                float v = acc[i][j] + bias[gn];
                if (ACT) v = fmaxf(v, 0.f);
                if (sizeof(CT) == 2)
                    ((bf16*)C)[(size_t)gm * ldc + gn] = __float2bfloat16(v);
                else
                    ((float*)C)[(size_t)gm * ldc + gn] = v;
            }
        }
    }
}

// ---------------- conv head: c[n,o,w] = sum_t sum_k emb[t,w+k] * A[n,t,o,k] + convb[o] ----

__global__ __launch_bounds__(256) void conv_head(const int* __restrict__ target,
                                                 const float* __restrict__ emb,
                                                 const float* __restrict__ convw,
                                                 const float* __restrict__ convb,
                                                 float* __restrict__ c) {
    __shared__ float A[26 * 256];
    __shared__ float emb_s[26 * 128];
    __shared__ int tg[1000];
    int n = blockIdx.x, tid = threadIdx.x;
    for (int i = tid; i < 26 * 256; i += 256) A[i] = 0.f;
    for (int i = tid; i < 26 * 128; i += 256) emb_s[i] = emb[i];
    for (int i = tid; i < 1000; i += 256) tg[i] = target[n * 1000 + i];
    __syncthreads();
    int o = tid >> 3, k = tid & 7;
    const float* cw = convw + o * 8000 + k;
    for (int i = 0; i < 1000; i++) {
        int t = tg[i];
        A[t * 256 + tid] += cw[i * 8];
    }
    __syncthreads();
    for (int idx = tid; idx < 32 * 121; idx += 256) {
        int oo = idx / 121, w = idx % 121;
        float acc = convb[oo];
#pragma unroll
        for (int t = 0; t < 26; t++) {
            const float* er = &emb_s[t * 128 + w];
            const float* ar = &A[t * 256 + oo * 8];
#pragma unroll
            for (int kk = 0; kk < 8; kk++) acc += er[kk] * ar[kk];
        }
        c[(size_t)n * 3872 + idx] = acc;
    }
}

// ---------------- final N=1 matvec ----------------

__global__ __launch_bounds__(256) void rowdot(const float* __restrict__ f2,
                                              const float* __restrict__ Wo,
                                              const float* __restrict__ bo,
                                              float* __restrict__ out, int M, int K) {
    int row = blockIdx.x * 4 + (threadIdx.x >> 6);
    int lane = threadIdx.x & 63;
    if (row >= M) return;
    float acc = 0.f;
    for (int k = lane; k < K; k += 64) acc += f2[(size_t)row * K + k] * Wo[k];
    for (int off = 32; off; off >>= 1) acc += __shfl_down(acc, off);
    if (lane == 0) out[row] = acc + bo[0];
}

// ---------------- launch ----------------

extern "C" void kernel_launch(void* const* d_in, const int* in_sizes, int n_in, void* d_out,
                              int out_size, void* d_ws, size_t ws_size, hipStream_t stream) {
    const float* x = (const float*)d_in[0];
    const int* ei = (const int*)d_in[1];
    const int* batch = (const int*)d_in[2];
    const int* target = (const int*)d_in[3];
    const float* W1 = (const float*)d_in[4];
    const float* b1 = (const float*)d_in[5];
    const float* W2 = (const float*)d_in[6];
    const float* b2 = (const float*)d_in[7];
    const float* W3 = (const float*)d_in[8];
    const float* b3 = (const float*)d_in[9];
    const float* Wg1 = (const float*)d_in[10];
    const float* bg1 = (const float*)d_in[11];
    const float* Wg2 = (const float*)d_in[12];
    const float* bg2 = (const float*)d_in[13];
    const float* emb = (const float*)d_in[14];
    const float* convw = (const float*)d_in[15];
    const float* convb = (const float*)d_in[16];
    const float* Wxt = (const float*)d_in[17];
    const float* bxt = (const float*)d_in[18];
    const float* Wf1 = (const float*)d_in[19];
    const float* bf1 = (const float*)d_in[20];
    const float* Wf2 = (const float*)d_in[21];
    const float* bf2 = (const float*)d_in[22];
    const float* Wo = (const float*)d_in[23];
    const float* bo = (const float*)d_in[24];
    float* out = (float*)d_out;

    const int N = N_NODES, E = N_EDGES;
    const int NB = (N + 511) / 512;

    char* ws = (char*)d_ws;
    size_t off = 0;
    auto alloc = [&](size_t bytes) -> char* {
        char* p = ws + off;
        off = (off + bytes + 255) & ~(size_t)255;
        return p;
    };
    int* cnt = (int*)alloc((size_t)N * 4);
    int* rowptr = (int*)alloc((size_t)(N + 1) * 4);
    int* bsum = (int*)alloc(512 * 4);
    int* col = (int*)alloc((size_t)E * 4);
    float* dinv = (float*)alloc((size_t)N * 4);
    unsigned int* g3bits = (unsigned int*)alloc((size_t)N_GRAPHS * 312 * 4);
    float* gg = (float*)alloc((size_t)N_GRAPHS * 1024 * 4);
    float* cbuf = (float*)alloc((size_t)N_GRAPHS * 3872 * 4);
    float* xc = (float*)alloc((size_t)N_GRAPHS * 256 * 4);
    float* f1 = (float*)alloc((size_t)N_GRAPHS * 1024 * 4);
    float* f2 = (float*)alloc((size_t)N_GRAPHS * 512 * 4);
    bf16* BA = (bf16*)alloc((size_t)N * 156 * 2);  // halves: B1=[N,78], B2=[N,78]; whole=[N,156]
    bf16* B3 = (bf16*)alloc((size_t)N * 156 * 2);  // [N,156]
    bf16* B1 = BA;
    bf16* B2 = BA + (size_t)N * 78;

    const int* srcp = ei;
    const int* dstp = ei + E;

    // CSR + norm (rebuilt every call: identical work per launch)
    hipMemsetAsync(cnt, 0, (size_t)N * 4, stream);
    count_edges<<<(E + 255) / 256, 256, 0, stream>>>(dstp, E, cnt);
    block_reduce<<<NB, 512, 0, stream>>>(cnt, N, bsum);
    scan_bsums<<<1, 512, 0, stream>>>(bsum, NB);
    block_scan_write<<<NB, 512, 0, stream>>>(cnt, bsum, N, rowptr);
    hipMemsetAsync(cnt, 0, (size_t)N * 4, stream);
    fill_csr<<<(E + 255) / 256, 256, 0, stream>>>(srcp, dstp, E, rowptr, cnt, col);
    compute_dinv<<<(N + 255) / 256, 256, 0, stream>>>(rowptr, N, dinv);
    hipMemsetAsync(g3bits, 0, (size_t)N_GRAPHS * 312 * 4, stream);

    dim3 g1((78 + 63) / 64, N / 64), g2((156 + 63) / 64, N / 64), g3g((312 + 63) / 64, N / 64);

    // layer 1: agg(x)[78] -> h1 = relu(agg @ W1 + b1) [78]
    aggregate<78, float><<<N, 128, 0, stream>>>(x, dinv, rowptr, col, B1);
    gemm_rrr<bf16, bf16, 1, 0><<<g1, 256, 0, stream>>>(B1, W1, b1, B2, N, 78, 78, 78, nullptr, nullptr);
    // layer 2: agg(h1)[78] -> h2 = relu(agg @ W2 + b2) [156]
    aggregate<78, bf16><<<N, 128, 0, stream>>>(B2, dinv, rowptr, col, B1);
    gemm_rrr<bf16, bf16, 1, 0><<<g2, 256, 0, stream>>>(B1, W2, b2, B3, N, 156, 78, 156, nullptr, nullptr);
    // layer 3: agg(h2)[156] -> fused relu(gemm) + segment_max -> g3
    aggregate<156, bf16><<<N, 192, 0, stream>>>(B3, dinv, rowptr, col, BA);
    gemm_rrr<bf16, float, 1, 1><<<g3g, 256, 0, stream>>>(BA, W3, b3, (float*)nullptr, N, 312, 156, 0,
                                                         batch, g3bits);

    // graph head (g3bits holds non-negative floats)
    const float* g3f = (const float*)g3bits;
    dim3 gg1((1024 + 63) / 64, (N_GRAPHS + 63) / 64);
    gemm_rrr<float, float, 1, 0><<<gg1, 256, 0, stream>>>(g3f, Wg1, bg1, gg, N_GRAPHS, 1024, 312,
                                                          1024, nullptr, nullptr);
    dim3 gg2((128 + 63) / 64, (N_GRAPHS + 63) / 64);
    gemm_rrr<float, float, 0, 0><<<gg2, 256, 0, stream>>>(gg, Wg2, bg2, xc, N_GRAPHS, 128, 1024,
                                                          256, nullptr, nullptr);

    // conv head
    conv_head<<<N_GRAPHS, 256, 0, stream>>>(target, emb, convw, convb, cbuf);
    gemm_rrr<float, float, 0, 0><<<gg2, 256, 0, stream>>>(cbuf, Wxt, bxt, xc + 128, N_GRAPHS, 128,
                                                          3872, 256, nullptr, nullptr);

    // final MLP
    gemm_rrr<float, float, 1, 0><<<gg1, 256, 0, stream>>>(xc, Wf1, bf1, f1, N_GRAPHS, 1024, 256,
                                                          1024, nullptr, nullptr);
    dim3 gg3((512 + 63) / 64, (N_GRAPHS + 63) / 64);
    gemm_rrr<float, float, 1, 0><<<gg3, 256, 0, stream>>>(f1, Wf2, bf2, f2, N_GRAPHS, 512, 1024,
                                                          512, nullptr, nullptr);
    rowdot<<<(N_GRAPHS + 3) / 4, 256, 0, stream>>>(f2, Wo, bo, out, N_GRAPHS, 512);
}

// Round 3
// 1608.574 us; speedup vs baseline: 1.6808x; 1.6808x over previous
//
#include <hip/hip_runtime.h>
#include <hip/hip_bf16.h>

#define N_NODES 200000
#define N_EDGES 800000
#define N_GRAPHS 512

typedef __hip_bfloat16 bf16;

__device__ inline float toF(float v) { return v; }
__device__ inline float toF(bf16 v) { return __bfloat162float(v); }

// ---------------- CSR build ----------------

__global__ __launch_bounds__(256) void count_edges(const int* __restrict__ dst, int E,
                                                   int* __restrict__ cnt) {
    int e = blockIdx.x * 256 + threadIdx.x;
    if (e < E) atomicAdd(&cnt[dst[e]], 1);
}

__global__ __launch_bounds__(512) void block_reduce(const int* __restrict__ in, int n,
                                                    int* __restrict__ bsum) {
    __shared__ int s[512];
    int i = blockIdx.x * 512 + threadIdx.x;
    s[threadIdx.x] = (i < n) ? in[i] : 0;
    __syncthreads();
    for (int off = 256; off; off >>= 1) {
        if (threadIdx.x < off) s[threadIdx.x] += s[threadIdx.x + off];
        __syncthreads();
    }
    if (threadIdx.x == 0) bsum[blockIdx.x] = s[0];
}

__global__ __launch_bounds__(512) void scan_bsums(int* bsum, int nb) {
    __shared__ int buf[2][512];
    int t = threadIdx.x;
    int v = (t < nb) ? bsum[t] : 0;
    buf[0][t] = v;
    __syncthreads();
    int src = 0;
    for (int off = 1; off < 512; off <<= 1) {
        int x = buf[src][t];
        if (t >= off) x += buf[src][t - off];
        buf[src ^ 1][t] = x;
        src ^= 1;
        __syncthreads();
    }
    if (t < nb) bsum[t] = buf[src][t] - v;  // exclusive
}

__global__ __launch_bounds__(512) void block_scan_write(const int* __restrict__ cnt,
                                                        const int* __restrict__ bsum, int n,
                                                        int* __restrict__ rowptr) {
    __shared__ int buf[2][512];
    int t = threadIdx.x;
    int i = blockIdx.x * 512 + t;
    int v = (i < n) ? cnt[i] : 0;
    buf[0][t] = v;
    __syncthreads();
    int src = 0;
    for (int off = 1; off < 512; off <<= 1) {
        int x = buf[src][t];
        if (t >= off) x += buf[src][t - off];
        buf[src ^ 1][t] = x;
        src ^= 1;
        __syncthreads();
    }
    int incl = buf[src][t];
    int base = bsum[blockIdx.x];
    if (i < n) rowptr[i] = base + incl - v;
    if (i == n - 1) rowptr[n] = base + incl;
}

__global__ __launch_bounds__(256) void fill_csr(const int* __restrict__ src,
                                                const int* __restrict__ dst, int E,
                                                const int* __restrict__ rowptr,
                                                int* __restrict__ cur, int* __restrict__ col) {
    int e = blockIdx.x * 256 + threadIdx.x;
    if (e < E) {
        int d = dst[e];
        int p = atomicAdd(&cur[d], 1);
        col[rowptr[d] + p] = src[e];
    }
}

__global__ __launch_bounds__(256) void compute_dinv(const int* __restrict__ rowptr, int n,
                                                    float* __restrict__ dinv) {
    int v = blockIdx.x * 256 + threadIdx.x;
    if (v < n) {
        int deg = rowptr[v + 1] - rowptr[v] + 1;  // +1 self loop
        dinv[v] = rsqrtf((float)deg);
    }
}

// ---------------- GCN aggregation: out[v] = dinv[v]*(dinv[v]*X[v] + sum dinv[u]*X[u]) ------

template <int F, typename TIN>
__global__ __launch_bounds__(256) void aggregate(const TIN* __restrict__ X,
                                                 const float* __restrict__ dinv,
                                                 const int* __restrict__ rowptr,
                                                 const int* __restrict__ col,
                                                 bf16* __restrict__ out) {
    int v = blockIdx.x;
    int f = threadIdx.x;
    int r0 = rowptr[v], r1 = rowptr[v + 1];
    float dv = dinv[v];
    float acc = 0.f;
    if (f < F) acc = toF(X[(size_t)v * F + f]) * dv;
    for (int e = r0; e < r1; ++e) {
        int u = col[e];
        float du = dinv[u];
        if (f < F) acc += toF(X[(size_t)u * F + f]) * du;
    }
    if (f < F) out[(size_t)v * F + f] = __float2bfloat16(acc * dv);
}

// ------- node GEMM: C = act(A[M,K] @ B[K,N] + bias[N]); optional fused relu+segment_max ---

template <typename AT, typename CT, int ACT, int SEGMAX>
__global__ __launch_bounds__(256) void gemm_rrr(const AT* __restrict__ A,
                                                const float* __restrict__ B,
                                                const float* __restrict__ bias,
                                                CT* __restrict__ C, int M, int N, int K, int ldc,
                                                const int* __restrict__ batch,
                                                unsigned int* __restrict__ g3bits) {
    __shared__ float As[16][68];
    __shared__ float Bs[16][68];
    __shared__ float red[16][64];
    int tid = threadIdx.x;
    int bx = blockIdx.x, by = blockIdx.y;
    int tx = tid & 15, ty = tid >> 4;
    int m0 = by * 64 + ty * 4;
    int n0 = bx * 64 + tx * 4;
    float acc[4][4] = {};
    for (int kt = 0; kt < K; kt += 16) {
#pragma unroll
        for (int l = 0; l < 4; l++) {
            int idx = tid + l * 256;
            int m_l = idx >> 4, k_l = idx & 15;
            int gm = by * 64 + m_l, gk = kt + k_l;
            As[k_l][m_l] = (gm < M && gk < K) ? toF(A[(size_t)gm * K + gk]) : 0.f;
        }
#pragma unroll
        for (int l = 0; l < 4; l++) {
            int idx = tid + l * 256;
            int k_l = idx >> 6, n_l = idx & 63;
            int gk = kt + k_l, gn = bx * 64 + n_l;
            Bs[k_l][n_l] = (gk < K && gn < N) ? B[(size_t)gk * N + gn] : 0.f;
        }
        __syncthreads();
#pragma unroll
        for (int k = 0; k < 16; k++) {
            float a0 = As[k][ty * 4 + 0], a1 = As[k][ty * 4 + 1];
            float a2 = As[k][ty * 4 + 2], a3 = As[k][ty * 4 + 3];
            float b0 = Bs[k][tx * 4 + 0], b1 = Bs[k][tx * 4 + 1];
            float b2 = Bs[k][tx * 4 + 2], b3 = Bs[k][tx * 4 + 3];
            acc[0][0] += a0 * b0; acc[0][1] += a0 * b1; acc[0][2] += a0 * b2; acc[0][3] += a0 * b3;
            acc[1][0] += a1 * b0; acc[1][1] += a1 * b1; acc[1][2] += a1 * b2; acc[1][3] += a1 * b3;
            acc[2][0] += a2 * b0; acc[2][1] += a2 * b1; acc[2][2] += a2 * b2; acc[2][3] += a2 * b3;
            acc[3][0] += a3 * b0; acc[3][1] += a3 * b1; acc[3][2] += a3 * b2; acc[3][3] += a3 * b3;
        }
        __syncthreads();
    }

    if (SEGMAX) {
        int mblk = by * 64;
        bool uni = (mblk + 63 < M) && (batch[mblk] == batch[mblk + 63]);
        if (uni) {
#pragma unroll
            for (int j = 0; j < 4; j++) {
                int gn = n0 + j;
                float v = 0.f;
                if (gn < N) {
                    float bj = bias[gn];
#pragma unroll
                    for (int i = 0; i < 4; i++) v = fmaxf(v, acc[i][j] + bj);
                }
                red[ty][tx * 4 + j] = v;
            }
            __syncthreads();
            if (tid < 64) {
                int gn = bx * 64 + tid;
                if (gn < N) {
                    float m = red[0][tid];
#pragma unroll
                    for (int r = 1; r < 16; r++) m = fmaxf(m, red[r][tid]);
                    atomicMax(&g3bits[(size_t)batch[mblk] * N + gn], __float_as_uint(m));
                }
            }
        } else {
#pragma unroll
            for (int j = 0; j < 4; j++) {
                int gn = n0 + j;
                if (gn < N) {
                    float bj = bias[gn];
#pragma unroll
                    for (int i = 0; i < 4; i++) {
                        int gm = m0 + i;
                        if (gm < M) {
                            float v = fmaxf(acc[i][j] + bj, 0.f);
                            atomicMax(&g3bits[(size_t)batch[gm] * N + gn], __float_as_uint(v));
                        }
                    }
                }
            }
        }
        return;
    }

#pragma unroll
    for (int i = 0; i < 4; i++) {
#pragma unroll
        for (int j = 0; j < 4; j++) {
            int gm = m0 + i, gn = n0 + j;
            if (gm < M && gn < N) {
                float v = acc[i][j] + bias[gn];
                if (ACT) v = fmaxf(v, 0.f);
                if (sizeof(CT) == 2)
                    ((bf16*)C)[(size_t)gm * ldc + gn] = __float2bfloat16(v);
                else
                    ((float*)C)[(size_t)gm * ldc + gn] = v;
            }
        }
    }
}

// ---------------- head GEMMs: split-K, atomicAdd into bias-initialized C ----------------
// C[m, n] += sum_{k in chunk} actA(A[m,k]) * B[k,n]; A row-stride == K for all uses.

__global__ __launch_bounds__(256) void init_bias(float* __restrict__ C,
                                                 const float* __restrict__ bias, int M, int N,
                                                 int ldc) {
    int idx = blockIdx.x * 256 + threadIdx.x;
    if (idx < M * N) C[(size_t)(idx / N) * ldc + (idx % N)] = bias[idx % N];
}

template <int RELUA>
__global__ __launch_bounds__(256) void gemm_splitk(const float* __restrict__ A,
                                                   const float* __restrict__ B,
                                                   float* __restrict__ C, int M, int N, int K,
                                                   int ldc, int Kc) {
    __shared__ float As[16][17];
    __shared__ float Bs[16][64];
    int bx = blockIdx.x, by = blockIdx.y, bz = blockIdx.z;
    int tid = threadIdx.x;
    int lane = tid & 63, wy = tid >> 6;
    int n0 = bx * 64, m0 = by * 16;
    int k0 = bz * Kc, k1 = min(K, k0 + Kc);
    float acc[4] = {0.f, 0.f, 0.f, 0.f};
    for (int kt = k0; kt < k1; kt += 16) {
        {
            int r = tid >> 4, kk = tid & 15;
            int gm = m0 + r, gk = kt + kk;
            float v = (gk < k1 && gm < M) ? A[(size_t)gm * K + gk] : 0.f;
            if (RELUA) v = fmaxf(v, 0.f);
            As[kk][r] = v;
        }
#pragma unroll
        for (int l = 0; l < 4; l++) {
            int kk = wy + l * 4;
            int gk = kt + kk, gn = n0 + lane;
            Bs[kk][lane] = (gk < k1 && gn < N) ? B[(size_t)gk * N + gn] : 0.f;
        }
        __syncthreads();
#pragma unroll
        for (int kk = 0; kk < 16; kk++) {
            float b = Bs[kk][lane];
#pragma unroll
            for (int r = 0; r < 4; r++) acc[r] += As[kk][wy * 4 + r] * b;
        }
        __syncthreads();
    }
    int gn = n0 + lane;
    if (gn < N) {
#pragma unroll
        for (int r = 0; r < 4; r++) {
            int gm = m0 + wy * 4 + r;
            if (gm < M) atomicAdd(&C[(size_t)gm * ldc + gn], acc[r]);
        }
    }
}

// ---------------- conv head: c[n,o,w] = sum_t sum_k emb[t,w+k] * A[n,t,o,k] + convb[o] ----

__global__ __launch_bounds__(256) void conv_head(const int* __restrict__ target,
                                                 const float* __restrict__ emb,
                                                 const float* __restrict__ convw,
                                                 const float* __restrict__ convb,
                                                 float* __restrict__ c) {
    __shared__ float A[26 * 256];
    __shared__ float emb_s[26 * 128];
    __shared__ int tg[1000];
    int n = blockIdx.x, tid = threadIdx.x;
    for (int i = tid; i < 26 * 256; i += 256) A[i] = 0.f;
    for (int i = tid; i < 26 * 128; i += 256) emb_s[i] = emb[i];
    for (int i = tid; i < 1000; i += 256) tg[i] = target[n * 1000 + i];
    __syncthreads();
    int o = tid >> 3, k = tid & 7;
    const float* cw = convw + o * 8000 + k;
    for (int i = 0; i < 1000; i++) {
        int t = tg[i];
        A[t * 256 + tid] += cw[i * 8];
    }
    __syncthreads();
    for (int idx = tid; idx < 32 * 121; idx += 256) {
        int oo = idx / 121, w = idx % 121;
        float acc = convb[oo];
#pragma unroll
        for (int t = 0; t < 26; t++) {
            const float* er = &emb_s[t * 128 + w];
            const float* ar = &A[t * 256 + oo * 8];
#pragma unroll
            for (int kk = 0; kk < 8; kk++) acc += er[kk] * ar[kk];
        }
        c[(size_t)n * 3872 + idx] = acc;
    }
}

// ---------------- final N=1 matvec (relu on load) ----------------

__global__ __launch_bounds__(256) void rowdot(const float* __restrict__ f2,
                                              const float* __restrict__ Wo,
                                              const float* __restrict__ bo,
                                              float* __restrict__ out, int M, int K) {
    int row = blockIdx.x * 4 + (threadIdx.x >> 6);
    int lane = threadIdx.x & 63;
    if (row >= M) return;
    float acc = 0.f;
    for (int k = lane; k < K; k += 64) acc += fmaxf(f2[(size_t)row * K + k], 0.f) * Wo[k];
    for (int off = 32; off; off >>= 1) acc += __shfl_down(acc, off);
    if (lane == 0) out[row] = acc + bo[0];
}

// ---------------- launch ----------------

extern "C" void kernel_launch(void* const* d_in, const int* in_sizes, int n_in, void* d_out,
                              int out_size, void* d_ws, size_t ws_size, hipStream_t stream) {
    const float* x = (const float*)d_in[0];
    const int* ei = (const int*)d_in[1];
    const int* batch = (const int*)d_in[2];
    const int* target = (const int*)d_in[3];
    const float* W1 = (const float*)d_in[4];
    const float* b1 = (const float*)d_in[5];
    const float* W2 = (const float*)d_in[6];
    const float* b2 = (const float*)d_in[7];
    const float* W3 = (const float*)d_in[8];
    const float* b3 = (const float*)d_in[9];
    const float* Wg1 = (const float*)d_in[10];
    const float* bg1 = (const float*)d_in[11];
    const float* Wg2 = (const float*)d_in[12];
    const float* bg2 = (const float*)d_in[13];
    const float* emb = (const float*)d_in[14];
    const float* convw = (const float*)d_in[15];
    const float* convb = (const float*)d_in[16];
    const float* Wxt = (const float*)d_in[17];
    const float* bxt = (const float*)d_in[18];
    const float* Wf1 = (const float*)d_in[19];
    const float* bf1 = (const float*)d_in[20];
    const float* Wf2 = (const float*)d_in[21];
    const float* bf2 = (const float*)d_in[22];
    const float* Wo = (const float*)d_in[23];
    const float* bo = (const float*)d_in[24];
    float* out = (float*)d_out;

    const int N = N_NODES, E = N_EDGES;
    const int NB = (N + 511) / 512;

    char* ws = (char*)d_ws;
    size_t off = 0;
    auto alloc = [&](size_t bytes) -> char* {
        char* p = ws + off;
        off = (off + bytes + 255) & ~(size_t)255;
        return p;
    };
    int* cnt = (int*)alloc((size_t)N * 4);
    int* rowptr = (int*)alloc((size_t)(N + 1) * 4);
    int* bsum = (int*)alloc(512 * 4);
    int* col = (int*)alloc((size_t)E * 4);
    float* dinv = (float*)alloc((size_t)N * 4);
    unsigned int* g3bits = (unsigned int*)alloc((size_t)N_GRAPHS * 312 * 4);
    float* gg = (float*)alloc((size_t)N_GRAPHS * 1024 * 4);
    float* cbuf = (float*)alloc((size_t)N_GRAPHS * 3872 * 4);
    float* xc = (float*)alloc((size_t)N_GRAPHS * 256 * 4);
    float* f1 = (float*)alloc((size_t)N_GRAPHS * 1024 * 4);
    float* f2 = (float*)alloc((size_t)N_GRAPHS * 512 * 4);
    bf16* BA = (bf16*)alloc((size_t)N * 156 * 2);  // halves: B1=[N,78], B2=[N,78]; whole=[N,156]
    bf16* B3 = (bf16*)alloc((size_t)N * 156 * 2);  // [N,156]
    bf16* B1 = BA;
    bf16* B2 = BA + (size_t)N * 78;

    const int* srcp = ei;
    const int* dstp = ei + E;

    // CSR + norm (rebuilt every call: identical work per launch)
    hipMemsetAsync(cnt, 0, (size_t)N * 4, stream);
    count_edges<<<(E + 255) / 256, 256, 0, stream>>>(dstp, E, cnt);
    block_reduce<<<NB, 512, 0, stream>>>(cnt, N, bsum);
    scan_bsums<<<1, 512, 0, stream>>>(bsum, NB);
    block_scan_write<<<NB, 512, 0, stream>>>(cnt, bsum, N, rowptr);
    hipMemsetAsync(cnt, 0, (size_t)N * 4, stream);
    fill_csr<<<(E + 255) / 256, 256, 0, stream>>>(srcp, dstp, E, rowptr, cnt, col);
    compute_dinv<<<(N + 255) / 256, 256, 0, stream>>>(rowptr, N, dinv);
    hipMemsetAsync(g3bits, 0, (size_t)N_GRAPHS * 312 * 4, stream);

    // bias-init all split-K outputs (only dependent on ws — run upfront)
    init_bias<<<(512 * 1024 + 255) / 256, 256, 0, stream>>>(gg, bg1, 512, 1024, 1024);
    init_bias<<<(512 * 128 + 255) / 256, 256, 0, stream>>>(xc, bg2, 512, 128, 256);
    init_bias<<<(512 * 128 + 255) / 256, 256, 0, stream>>>(xc + 128, bxt, 512, 128, 256);
    init_bias<<<(512 * 1024 + 255) / 256, 256, 0, stream>>>(f1, bf1, 512, 1024, 1024);
    init_bias<<<(512 * 512 + 255) / 256, 256, 0, stream>>>(f2, bf2, 512, 512, 512);

    dim3 g1((78 + 63) / 64, N / 64), g2((156 + 63) / 64, N / 64), g3g((312 + 63) / 64, N / 64);

    // layer 1: agg(x)[78] -> h1 = relu(agg @ W1 + b1) [78]
    aggregate<78, float><<<N, 128, 0, stream>>>(x, dinv, rowptr, col, B1);
    gemm_rrr<bf16, bf16, 1, 0><<<g1, 256, 0, stream>>>(B1, W1, b1, B2, N, 78, 78, 78, nullptr, nullptr);
    // layer 2: agg(h1)[78] -> h2 = relu(agg @ W2 + b2) [156]
    aggregate<78, bf16><<<N, 128, 0, stream>>>(B2, dinv, rowptr, col, B1);
    gemm_rrr<bf16, bf16, 1, 0><<<g2, 256, 0, stream>>>(B1, W2, b2, B3, N, 156, 78, 156, nullptr, nullptr);
    // layer 3: agg(h2)[156] -> fused relu(gemm) + segment_max -> g3bits
    aggregate<156, bf16><<<N, 192, 0, stream>>>(B3, dinv, rowptr, col, BA);
    gemm_rrr<bf16, float, 1, 1><<<g3g, 256, 0, stream>>>(BA, W3, b3, (float*)nullptr, N, 312, 156, 0,
                                                         batch, g3bits);

    // graph head (split-K; C pre-initialized with bias)
    const float* g3f = (const float*)g3bits;
    gemm_splitk<0><<<dim3(16, 32, 2), 256, 0, stream>>>(g3f, Wg1, gg, 512, 1024, 312, 1024, 160);
    gemm_splitk<1><<<dim3(2, 32, 8), 256, 0, stream>>>(gg, Wg2, xc, 512, 128, 1024, 256, 128);

    // conv head
    conv_head<<<N_GRAPHS, 256, 0, stream>>>(target, emb, convw, convb, cbuf);
    gemm_splitk<0><<<dim3(2, 32, 16), 256, 0, stream>>>(cbuf, Wxt, xc + 128, 512, 128, 3872, 256, 256);

    // final MLP
    gemm_splitk<0><<<dim3(16, 32, 2), 256, 0, stream>>>(xc, Wf1, f1, 512, 1024, 256, 1024, 128);
    gemm_splitk<1><<<dim3(8, 32, 8), 256, 0, stream>>>(f1, Wf2, f2, 512, 512, 1024, 512, 128);
    rowdot<<<(N_GRAPHS + 3) / 4, 256, 0, stream>>>(f2, Wo, bo, out, N_GRAPHS, 512);
}

// Round 4
// 961.227 us; speedup vs baseline: 2.8128x; 1.6735x over previous
//
#include <hip/hip_runtime.h>
#include <hip/hip_bf16.h>

#define N_NODES 200000
#define N_EDGES 800000
#define N_GRAPHS 512

typedef __attribute__((ext_vector_type(8))) short short8v;
typedef __attribute__((ext_vector_type(4))) float f32x4;
typedef __attribute__((ext_vector_type(2))) float f32x2;
typedef __attribute__((ext_vector_type(2))) unsigned int u32x2;
typedef __attribute__((ext_vector_type(4))) unsigned int u32x4;

__device__ inline float bf2f(unsigned int u) {
    union { unsigned int i; float f; } c;
    c.i = u << 16;
    return c.f;
}
__device__ inline unsigned short f2bf(float f) {
    union { __hip_bfloat16 h; unsigned short u; } c;
    c.h = __float2bfloat16(f);
    return c.u;
}

// ---------------- CSR build ----------------

__global__ __launch_bounds__(256) void count_edges(const int* __restrict__ dst, int E,
                                                   int* __restrict__ cnt) {
    int e = blockIdx.x * 256 + threadIdx.x;
    if (e < E) atomicAdd(&cnt[dst[e]], 1);
}

__global__ __launch_bounds__(512) void block_reduce(const int* __restrict__ in, int n,
                                                    int* __restrict__ bsum) {
    __shared__ int s[512];
    int i = blockIdx.x * 512 + threadIdx.x;
    s[threadIdx.x] = (i < n) ? in[i] : 0;
    __syncthreads();
    for (int off = 256; off; off >>= 1) {
        if (threadIdx.x < off) s[threadIdx.x] += s[threadIdx.x + off];
        __syncthreads();
    }
    if (threadIdx.x == 0) bsum[blockIdx.x] = s[0];
}

__global__ __launch_bounds__(512) void scan_bsums(int* bsum, int nb) {
    __shared__ int buf[2][512];
    int t = threadIdx.x;
    int v = (t < nb) ? bsum[t] : 0;
    buf[0][t] = v;
    __syncthreads();
    int src = 0;
    for (int off = 1; off < 512; off <<= 1) {
        int x = buf[src][t];
        if (t >= off) x += buf[src][t - off];
        buf[src ^ 1][t] = x;
        src ^= 1;
        __syncthreads();
    }
    if (t < nb) bsum[t] = buf[src][t] - v;  // exclusive
}

__global__ __launch_bounds__(512) void block_scan_write(const int* __restrict__ cnt,
                                                        const int* __restrict__ bsum, int n,
                                                        int* __restrict__ rowptr) {
    __shared__ int buf[2][512];
    int t = threadIdx.x;
    int i = blockIdx.x * 512 + t;
    int v = (i < n) ? cnt[i] : 0;
    buf[0][t] = v;
    __syncthreads();
    int src = 0;
    for (int off = 1; off < 512; off <<= 1) {
        int x = buf[src][t];
        if (t >= off) x += buf[src][t - off];
        buf[src ^ 1][t] = x;
        src ^= 1;
        __syncthreads();
    }
    int incl = buf[src][t];
    int base = bsum[blockIdx.x];
    if (i < n) rowptr[i] = base + incl - v;
    if (i == n - 1) rowptr[n] = base + incl;
}

__global__ __launch_bounds__(256) void fill_csr(const int* __restrict__ src,
                                                const int* __restrict__ dst, int E,
                                                const int* __restrict__ rowptr,
                                                int* __restrict__ cur, int* __restrict__ col) {
    int e = blockIdx.x * 256 + threadIdx.x;
    if (e < E) {
        int d = dst[e];
        int p = atomicAdd(&cur[d], 1);
        col[rowptr[d] + p] = src[e];
    }
}

__global__ __launch_bounds__(256) void compute_dinv(const int* __restrict__ rowptr, int n,
                                                    float* __restrict__ dinv) {
    int v = blockIdx.x * 256 + threadIdx.x;
    if (v < n) {
        int deg = rowptr[v + 1] - rowptr[v] + 1;  // +1 self loop
        dinv[v] = rsqrtf((float)deg);
    }
}

__global__ __launch_bounds__(64) void graph_bounds(const int* __restrict__ batch, int n, int ng,
                                                   int* __restrict__ gstart) {
    int b = blockIdx.x * 64 + threadIdx.x;
    if (b > ng) return;
    if (b == ng) { gstart[ng] = n; return; }
    int lo = 0, hi = n;
    while (lo < hi) {
        int mid = (lo + hi) >> 1;
        if (batch[mid] < b) lo = mid + 1; else hi = mid;
    }
    gstart[b] = lo;
}

// ------- aggregation: out[v] = dinv[v]*(dinv[v]*X[v] + sum dinv[u]*X[u]) --------------
// agg1: f32 [N][78] -> bf16 [N][80] (cols 78,79 = 0). thread = (node, 2-float chunk)

__global__ __launch_bounds__(256) void aggregate1(const float* __restrict__ X,
                                                  const float* __restrict__ dinv,
                                                  const int* __restrict__ rowptr,
                                                  const int* __restrict__ col,
                                                  unsigned short* __restrict__ out) {
    int tid = threadIdx.x;
    if (tid >= 240) return;
    int v = blockIdx.x * 6 + tid / 40;
    int c = tid % 40;
    if (v >= N_NODES) return;
    if (c == 39) {  // pad cols 78,79
        *(unsigned int*)(out + (size_t)v * 80 + 78) = 0u;
        return;
    }
    float dv = dinv[v];
    f32x2 xv = *(const f32x2*)(X + (size_t)v * 78 + c * 2);
    float a0 = xv.x * dv, a1 = xv.y * dv;
    int r0 = rowptr[v], r1 = rowptr[v + 1];
    for (int e = r0; e < r1; ++e) {
        int u = col[e];
        float du = dinv[u];
        f32x2 xu = *(const f32x2*)(X + (size_t)u * 78 + c * 2);
        a0 += du * xu.x;
        a1 += du * xu.y;
    }
    unsigned int pack = ((unsigned int)f2bf(a1 * dv) << 16) | f2bf(a0 * dv);
    *(unsigned int*)(out + (size_t)v * 80 + c * 2) = pack;
}

// agg2: bf16 [N][80] -> bf16 [N][80]. thread = (node, 4-elem chunk)

__global__ __launch_bounds__(256) void aggregate2(const unsigned short* __restrict__ X,
                                                  const float* __restrict__ dinv,
                                                  const int* __restrict__ rowptr,
                                                  const int* __restrict__ col,
                                                  unsigned short* __restrict__ out) {
    int tid = threadIdx.x;
    if (tid >= 240) return;
    int v = blockIdx.x * 12 + tid / 20;
    int c = tid % 20;
    if (v >= N_NODES) return;
    float dv = dinv[v];
    u32x2 xv = *(const u32x2*)(X + (size_t)v * 80 + c * 4);
    float a0 = bf2f(xv.x & 0xffffu) * dv, a1 = bf2f(xv.x >> 16) * dv;
    float a2 = bf2f(xv.y & 0xffffu) * dv, a3 = bf2f(xv.y >> 16) * dv;
    int r0 = rowptr[v], r1 = rowptr[v + 1];
    for (int e = r0; e < r1; ++e) {
        int u = col[e];
        float du = dinv[u];
        u32x2 xu = *(const u32x2*)(X + (size_t)u * 80 + c * 4);
        a0 += du * bf2f(xu.x & 0xffffu);
        a1 += du * bf2f(xu.x >> 16);
        a2 += du * bf2f(xu.y & 0xffffu);
        a3 += du * bf2f(xu.y >> 16);
    }
    u32x2 o;
    o.x = ((unsigned int)f2bf(a1 * dv) << 16) | f2bf(a0 * dv);
    o.y = ((unsigned int)f2bf(a3 * dv) << 16) | f2bf(a2 * dv);
    *(u32x2*)(out + (size_t)v * 80 + c * 4) = o;
}

// agg3: bf16 [N][160] -> bf16 [N][160]. thread = (node, 8-elem chunk)

__global__ __launch_bounds__(256) void aggregate3(const unsigned short* __restrict__ X,
                                                  const float* __restrict__ dinv,
                                                  const int* __restrict__ rowptr,
                                                  const int* __restrict__ col,
                                                  unsigned short* __restrict__ out) {
    int tid = threadIdx.x;
    if (tid >= 240) return;
    int v = blockIdx.x * 12 + tid / 20;
    int c = tid % 20;
    if (v >= N_NODES) return;
    float dv = dinv[v];
    u32x4 xv = *(const u32x4*)(X + (size_t)v * 160 + c * 8);
    float a0 = bf2f(xv.x & 0xffffu) * dv, a1 = bf2f(xv.x >> 16) * dv;
    float a2 = bf2f(xv.y & 0xffffu) * dv, a3 = bf2f(xv.y >> 16) * dv;
    float a4 = bf2f(xv.z & 0xffffu) * dv, a5 = bf2f(xv.z >> 16) * dv;
    float a6 = bf2f(xv.w & 0xffffu) * dv, a7 = bf2f(xv.w >> 16) * dv;
    int r0 = rowptr[v], r1 = rowptr[v + 1];
    for (int e = r0; e < r1; ++e) {
        int u = col[e];
        float du = dinv[u];
        u32x4 xu = *(const u32x4*)(X + (size_t)u * 160 + c * 8);
        a0 += du * bf2f(xu.x & 0xffffu);
        a1 += du * bf2f(xu.x >> 16);
        a2 += du * bf2f(xu.y & 0xffffu);
        a3 += du * bf2f(xu.y >> 16);
        a4 += du * bf2f(xu.z & 0xffffu);
        a5 += du * bf2f(xu.z >> 16);
        a6 += du * bf2f(xu.w & 0xffffu);
        a7 += du * bf2f(xu.w >> 16);
    }
    u32x4 o;
    o.x = ((unsigned int)f2bf(a1 * dv) << 16) | f2bf(a0 * dv);
    o.y = ((unsigned int)f2bf(a3 * dv) << 16) | f2bf(a2 * dv);
    o.z = ((unsigned int)f2bf(a5 * dv) << 16) | f2bf(a4 * dv);
    o.w = ((unsigned int)f2bf(a7 * dv) << 16) | f2bf(a6 * dv);
    *(u32x4*)(out + (size_t)v * 160 + c * 8) = o;
}

// ------- MFMA node GEMM: out = relu(A @ W + bias), bf16 in/out, B staged in LDS -------
// mfma_f32_16x16x32_bf16 layouts: A: row=lane&15, k=8*(lane>>4)+j; B: col=lane&15, same k;
// D: col=lane&15, row=4*(lane>>4)+r.  B LDS pre-arranged in fragment-linear order.

template <int KREAL, int NREAL, int LDA, int LDC, int NF, int KS>
__global__ __launch_bounds__(256) void gemm_mfma_node(const unsigned short* __restrict__ A,
                                                      const float* __restrict__ W,
                                                      const float* __restrict__ bias,
                                                      unsigned short* __restrict__ Cout, int M) {
    __shared__ unsigned short Bs[NF * KS * 64 * 8];
    int tid = threadIdx.x;
    for (int idx = tid; idx < NF * KS * 64; idx += 256) {
        int l = idx & 63, ks = (idx >> 6) % KS, nf = idx / (64 * KS);
        int k0 = ks * 32 + 8 * (l >> 4);
        int cc = nf * 16 + (l & 15);
        short8v t;
#pragma unroll
        for (int j = 0; j < 8; j++) {
            int k = k0 + j;
            float w = (k < KREAL && cc < NREAL) ? W[(size_t)k * NREAL + cc] : 0.f;
            t[j] = (short)f2bf(w);
        }
        *(short8v*)&Bs[idx * 8] = t;
    }
    __syncthreads();

    int lane = tid & 63, wid = tid >> 6;
    int m0 = blockIdx.x * 128 + wid * 32;
    float biasr[NF];
#pragma unroll
    for (int nf = 0; nf < NF; nf++) {
        int cc = nf * 16 + (lane & 15);
        biasr[nf] = (cc < NREAL) ? bias[cc] : 0.f;
    }
    f32x4 acc[2][NF];
#pragma unroll
    for (int mf = 0; mf < 2; mf++)
#pragma unroll
        for (int nf = 0; nf < NF; nf++) acc[mf][nf] = (f32x4){0.f, 0.f, 0.f, 0.f};

    int ra = min(m0 + (lane & 15), M - 1);
    int rb = min(m0 + 16 + (lane & 15), M - 1);
#pragma unroll
    for (int ks = 0; ks < KS; ks++) {
        int koff = ks * 32 + 8 * (lane >> 4);
        short8v a0 = *(const short8v*)(A + (size_t)ra * LDA + koff);
        short8v a1 = *(const short8v*)(A + (size_t)rb * LDA + koff);
#pragma unroll
        for (int nf = 0; nf < NF; nf++) {
            short8v b = *(const short8v*)&Bs[((nf * KS + ks) * 64 + lane) * 8];
            acc[0][nf] = __builtin_amdgcn_mfma_f32_16x16x32_bf16(a0, b, acc[0][nf], 0, 0, 0);
            acc[1][nf] = __builtin_amdgcn_mfma_f32_16x16x32_bf16(a1, b, acc[1][nf], 0, 0, 0);
        }
    }
#pragma unroll
    for (int mf = 0; mf < 2; mf++) {
#pragma unroll
        for (int nf = 0; nf < NF; nf++) {
            int cc = nf * 16 + (lane & 15);
#pragma unroll
            for (int r = 0; r < 4; r++) {
                int row = m0 + mf * 16 + 4 * (lane >> 4) + r;
                float v = fmaxf(acc[mf][nf][r] + biasr[nf], 0.f);
                unsigned short o = (cc < NREAL) ? f2bf(v) : (unsigned short)0;
                if (row < M) Cout[(size_t)row * LDC + cc] = o;
            }
        }
    }
}

// ------- layer-3 GEMM fused with per-graph segment-max: one block per graph, no atomics ----
// A bf16 [N][160] (K=156 padded), W3 f32 [156][312], out g3 f32 [512][312]

__global__ __launch_bounds__(256) void seg_gemm_max(const unsigned short* __restrict__ A,
                                                    const float* __restrict__ W3,
                                                    const float* __restrict__ b3,
                                                    const int* __restrict__ gstart,
                                                    float* __restrict__ g3) {
    __shared__ unsigned short Bs[10 * 5 * 64 * 8];  // 51.2 KB
    __shared__ float wmax[4][160];
    int g = blockIdx.x;
    int r0 = gstart[g], r1 = gstart[g + 1];
    int tid = threadIdx.x, lane = tid & 63, wid = tid >> 6;

    for (int nc = 0; nc < 2; nc++) {
        for (int idx = tid; idx < 3200; idx += 256) {
            int l = idx & 63, ks = (idx >> 6) % 5, nf = idx / 320;
            int k0 = ks * 32 + 8 * (l >> 4);
            int cc = nc * 160 + nf * 16 + (l & 15);
            short8v t;
#pragma unroll
            for (int j = 0; j < 8; j++) {
                int k = k0 + j;
                float w = (k < 156 && cc < 312) ? W3[(size_t)k * 312 + cc] : 0.f;
                t[j] = (short)f2bf(w);
            }
            *(short8v*)&Bs[idx * 8] = t;
        }
        __syncthreads();

        float biasr[10], cmax[10];
#pragma unroll
        for (int nf = 0; nf < 10; nf++) {
            int cc = nc * 160 + nf * 16 + (lane & 15);
            biasr[nf] = (cc < 312) ? b3[cc] : 0.f;
            cmax[nf] = 0.f;
        }

        for (int mt = r0 + wid * 32; mt < r1; mt += 128) {
            f32x4 acc[2][10];
#pragma unroll
            for (int mf = 0; mf < 2; mf++)
#pragma unroll
                for (int nf = 0; nf < 10; nf++) acc[mf][nf] = (f32x4){0.f, 0.f, 0.f, 0.f};
            int ra = min(mt + (lane & 15), N_NODES - 1);
            int rb = min(mt + 16 + (lane & 15), N_NODES - 1);
#pragma unroll
            for (int ks = 0; ks < 5; ks++) {
                int koff = ks * 32 + 8 * (lane >> 4);
                short8v a0 = *(const short8v*)(A + (size_t)ra * 160 + koff);
                short8v a1 = *(const short8v*)(A + (size_t)rb * 160 + koff);
#pragma unroll
                for (int nf = 0; nf < 10; nf++) {
                    short8v b = *(const short8v*)&Bs[((nf * 5 + ks) * 64 + lane) * 8];
                    acc[0][nf] = __builtin_amdgcn_mfma_f32_16x16x32_bf16(a0, b, acc[0][nf], 0, 0, 0);
                    acc[1][nf] = __builtin_amdgcn_mfma_f32_16x16x32_bf16(a1, b, acc[1][nf], 0, 0, 0);
                }
            }
#pragma unroll
            for (int mf = 0; mf < 2; mf++) {
#pragma unroll
                for (int nf = 0; nf < 10; nf++) {
#pragma unroll
                    for (int r = 0; r < 4; r++) {
                        int row = mt + mf * 16 + 4 * (lane >> 4) + r;
                        float v = fmaxf(acc[mf][nf][r] + biasr[nf], 0.f);
                        if (row < r1) cmax[nf] = fmaxf(cmax[nf], v);
                    }
                }
            }
        }
#pragma unroll
        for (int nf = 0; nf < 10; nf++) {
            float m = cmax[nf];
            m = fmaxf(m, __shfl_xor(m, 16));
            m = fmaxf(m, __shfl_xor(m, 32));
            if (lane < 16) wmax[wid][nf * 16 + lane] = m;
        }
        __syncthreads();
        if (tid < 160) {
            float m = fmaxf(fmaxf(wmax[0][tid], wmax[1][tid]), fmaxf(wmax[2][tid], wmax[3][tid]));
            int cc = nc * 160 + tid;
            if (cc < 312) g3[(size_t)g * 312 + cc] = m;
        }
        __syncthreads();
    }
}

// ---------------- head GEMMs: split-K, atomicAdd into bias-initialized C ----------------

__global__ __launch_bounds__(256) void init_bias(float* __restrict__ C,
                                                 const float* __restrict__ bias, int M, int N,
                                                 int ldc) {
    int idx = blockIdx.x * 256 + threadIdx.x;
    if (idx < M * N) C[(size_t)(idx / N) * ldc + (idx % N)] = bias[idx % N];
}

template <int RELUA>
__global__ __launch_bounds__(256) void gemm_splitk(const float* __restrict__ A,
                                                   const float* __restrict__ B,
                                                   float* __restrict__ C, int M, int N, int K,
                                                   int ldc, int Kc) {
    __shared__ float As[16][17];
    __shared__ float Bs[16][64];
    int bx = blockIdx.x, by = blockIdx.y, bz = blockIdx.z;
    int tid = threadIdx.x;
    int lane = tid & 63, wy = tid >> 6;
    int n0 = bx * 64, m0 = by * 16;
    int k0 = bz * Kc, k1 = min(K, k0 + Kc);
    float acc[4] = {0.f, 0.f, 0.f, 0.f};
    for (int kt = k0; kt < k1; kt += 16) {
        {
            int r = tid >> 4, kk = tid & 15;
            int gm = m0 + r, gk = kt + kk;
            float v = (gk < k1 && gm < M) ? A[(size_t)gm * K + gk] : 0.f;
            if (RELUA) v = fmaxf(v, 0.f);
            As[kk][r] = v;
        }
#pragma unroll
        for (int l = 0; l < 4; l++) {
            int kk = wy + l * 4;
            int gk = kt + kk, gn = n0 + lane;
            Bs[kk][lane] = (gk < k1 && gn < N) ? B[(size_t)gk * N + gn] : 0.f;
        }
        __syncthreads();
#pragma unroll
        for (int kk = 0; kk < 16; kk++) {
            float b = Bs[kk][lane];
#pragma unroll
            for (int r = 0; r < 4; r++) acc[r] += As[kk][wy * 4 + r] * b;
        }
        __syncthreads();
    }
    int gn = n0 + lane;
    if (gn < N) {
#pragma unroll
        for (int r = 0; r < 4; r++) {
            int gm = m0 + wy * 4 + r;
            if (gm < M) atomicAdd(&C[(size_t)gm * ldc + gn], acc[r]);
        }
    }
}

// ---------------- conv head: c[n,o,w] = sum_t sum_k emb[t,w+k] * A[n,t,o,k] + convb[o] ----

__global__ __launch_bounds__(256) void conv_head(const int* __restrict__ target,
                                                 const float* __restrict__ emb,
                                                 const float* __restrict__ convw,
                                                 const float* __restrict__ convb,
                                                 float* __restrict__ c) {
    __shared__ float A[26 * 256];
    __shared__ float emb_s[26 * 128];
    __shared__ int tg[1000];
    int n = blockIdx.x, tid = threadIdx.x;
    for (int i = tid; i < 26 * 256; i += 256) A[i] = 0.f;
    for (int i = tid; i < 26 * 128; i += 256) emb_s[i] = emb[i];
    for (int i = tid; i < 1000; i += 256) tg[i] = target[n * 1000 + i];
    __syncthreads();
    int o = tid >> 3, k = tid & 7;
    const float* cw = convw + o * 8000 + k;
    for (int i = 0; i < 1000; i++) {
        int t = tg[i];
        A[t * 256 + tid] += cw[i * 8];
    }
    __syncthreads();
    for (int idx = tid; idx < 32 * 121; idx += 256) {
        int oo = idx / 121, w = idx % 121;
        float acc = convb[oo];
#pragma unroll
        for (int t = 0; t < 26; t++) {
            const float* er = &emb_s[t * 128 + w];
            const float* ar = &A[t * 256 + oo * 8];
#pragma unroll
            for (int kk = 0; kk < 8; kk++) acc += er[kk] * ar[kk];
        }
        c[(size_t)n * 3872 + idx] = acc;
    }
}

// ---------------- final N=1 matvec (relu on load) ----------------

__global__ __launch_bounds__(256) void rowdot(const float* __restrict__ f2,
                                              const float* __restrict__ Wo,
                                              const float* __restrict__ bo,
                                              float* __restrict__ out, int M, int K) {
    int row = blockIdx.x * 4 + (threadIdx.x >> 6);
    int lane = threadIdx.x & 63;
    if (row >= M) return;
    float acc = 0.f;
    for (int k = lane; k < K; k += 64) acc += fmaxf(f2[(size_t)row * K + k], 0.f) * Wo[k];
    for (int off = 32; off; off >>= 1) acc += __shfl_down(acc, off);
    if (lane == 0) out[row] = acc + bo[0];
}

// ---------------- launch ----------------

extern "C" void kernel_launch(void* const* d_in, const int* in_sizes, int n_in, void* d_out,
                              int out_size, void* d_ws, size_t ws_size, hipStream_t stream) {
    const float* x = (const float*)d_in[0];
    const int* ei = (const int*)d_in[1];
    const int* batch = (const int*)d_in[2];
    const int* target = (const int*)d_in[3];
    const float* W1 = (const float*)d_in[4];
    const float* b1 = (const float*)d_in[5];
    const float* W2 = (const float*)d_in[6];
    const float* b2 = (const float*)d_in[7];
    const float* W3 = (const float*)d_in[8];
    const float* b3 = (const float*)d_in[9];
    const float* Wg1 = (const float*)d_in[10];
    const float* bg1 = (const float*)d_in[11];
    const float* Wg2 = (const float*)d_in[12];
    const float* bg2 = (const float*)d_in[13];
    const float* emb = (const float*)d_in[14];
    const float* convw = (const float*)d_in[15];
    const float* convb = (const float*)d_in[16];
    const float* Wxt = (const float*)d_in[17];
    const float* bxt = (const float*)d_in[18];
    const float* Wf1 = (const float*)d_in[19];
    const float* bf1 = (const float*)d_in[20];
    const float* Wf2 = (const float*)d_in[21];
    const float* bf2 = (const float*)d_in[22];
    const float* Wo = (const float*)d_in[23];
    const float* bo = (const float*)d_in[24];
    float* out = (float*)d_out;

    const int N = N_NODES, E = N_EDGES;
    const int NB = (N + 511) / 512;

    char* ws = (char*)d_ws;
    size_t off = 0;
    auto alloc = [&](size_t bytes) -> char* {
        char* p = ws + off;
        off = (off + bytes + 255) & ~(size_t)255;
        return p;
    };
    int* cnt = (int*)alloc((size_t)N * 4);
    int* rowptr = (int*)alloc((size_t)(N + 1) * 4);
    int* bsum = (int*)alloc(512 * 4);
    int* col = (int*)alloc((size_t)E * 4);
    float* dinv = (float*)alloc((size_t)N * 4);
    int* gstart = (int*)alloc((N_GRAPHS + 1) * 4);
    float* g3 = (float*)alloc((size_t)N_GRAPHS * 312 * 4);
    float* gg = (float*)alloc((size_t)N_GRAPHS * 1024 * 4);
    float* cbuf = (float*)alloc((size_t)N_GRAPHS * 3872 * 4);
    float* xc = (float*)alloc((size_t)N_GRAPHS * 256 * 4);
    float* f1 = (float*)alloc((size_t)N_GRAPHS * 1024 * 4);
    float* f2 = (float*)alloc((size_t)N_GRAPHS * 512 * 4);
    unsigned short* U = (unsigned short*)alloc((size_t)N * 160 * 2 + 512);    // agg1|h1, later agg3
    unsigned short* P160 = (unsigned short*)alloc((size_t)N * 160 * 2 + 512); // h2
    unsigned short* H1 = U + (size_t)N * 80;

    const int* srcp = ei;
    const int* dstp = ei + E;

    // CSR + norm
    hipMemsetAsync(cnt, 0, (size_t)N * 4, stream);
    count_edges<<<(E + 255) / 256, 256, 0, stream>>>(dstp, E, cnt);
    block_reduce<<<NB, 512, 0, stream>>>(cnt, N, bsum);
    scan_bsums<<<1, 512, 0, stream>>>(bsum, NB);
    block_scan_write<<<NB, 512, 0, stream>>>(cnt, bsum, N, rowptr);
    hipMemsetAsync(cnt, 0, (size_t)N * 4, stream);
    fill_csr<<<(E + 255) / 256, 256, 0, stream>>>(srcp, dstp, E, rowptr, cnt, col);
    compute_dinv<<<(N + 255) / 256, 256, 0, stream>>>(rowptr, N, dinv);
    graph_bounds<<<(N_GRAPHS + 1 + 63) / 64, 64, 0, stream>>>(batch, N, N_GRAPHS, gstart);

    // bias-init split-K outputs
    init_bias<<<(512 * 1024 + 255) / 256, 256, 0, stream>>>(gg, bg1, 512, 1024, 1024);
    init_bias<<<(512 * 128 + 255) / 256, 256, 0, stream>>>(xc, bg2, 512, 128, 256);
    init_bias<<<(512 * 128 + 255) / 256, 256, 0, stream>>>(xc + 128, bxt, 512, 128, 256);
    init_bias<<<(512 * 1024 + 255) / 256, 256, 0, stream>>>(f1, bf1, 512, 1024, 1024);
    init_bias<<<(512 * 512 + 255) / 256, 256, 0, stream>>>(f2, bf2, 512, 512, 512);

    const int MB = (N + 127) / 128;  // 1563

    // layer 1
    aggregate1<<<(N + 5) / 6, 256, 0, stream>>>(x, dinv, rowptr, col, U);
    gemm_mfma_node<78, 78, 80, 80, 5, 3><<<MB, 256, 0, stream>>>(U, W1, b1, H1, N);
    // layer 2
    aggregate2<<<(N + 11) / 12, 256, 0, stream>>>(H1, dinv, rowptr, col, U);
    gemm_mfma_node<78, 156, 80, 160, 10, 3><<<MB, 256, 0, stream>>>(U, W2, b2, P160, N);
    // layer 3 (fused with per-graph segment max)
    aggregate3<<<(N + 11) / 12, 256, 0, stream>>>(P160, dinv, rowptr, col, U);
    seg_gemm_max<<<N_GRAPHS, 256, 0, stream>>>(U, W3, b3, gstart, g3);

    // graph head
    gemm_splitk<0><<<dim3(16, 32, 2), 256, 0, stream>>>(g3, Wg1, gg, 512, 1024, 312, 1024, 160);
    gemm_splitk<1><<<dim3(2, 32, 8), 256, 0, stream>>>(gg, Wg2, xc, 512, 128, 1024, 256, 128);

    // conv head
    conv_head<<<N_GRAPHS, 256, 0, stream>>>(target, emb, convw, convb, cbuf);
    gemm_splitk<0><<<dim3(2, 32, 16), 256, 0, stream>>>(cbuf, Wxt, xc + 128, 512, 128, 3872, 256, 256);

    // final MLP
    gemm_splitk<0><<<dim3(16, 32, 2), 256, 0, stream>>>(xc, Wf1, f1, 512, 1024, 256, 1024, 128);
    gemm_splitk<1><<<dim3(8, 32, 8), 256, 0, stream>>>(f1, Wf2, f2, 512, 512, 1024, 512, 128);
    rowdot<<<(N_GRAPHS + 3) / 4, 256, 0, stream>>>(f2, Wo, bo, out, N_GRAPHS, 512);
}

// Round 5
// 864.451 us; speedup vs baseline: 3.1277x; 1.1119x over previous
//
#include <hip/hip_runtime.h>
#include <hip/hip_bf16.h>

#define N_NODES 200000
#define N_EDGES 800000
#define N_GRAPHS 512

typedef __attribute__((ext_vector_type(8))) short short8v;
typedef __attribute__((ext_vector_type(4))) float f32x4;
typedef __attribute__((ext_vector_type(2))) float f32x2;
typedef __attribute__((ext_vector_type(2))) unsigned int u32x2;
typedef __attribute__((ext_vector_type(4))) unsigned int u32x4;

__device__ inline float bf2f(unsigned int u) {
    union { unsigned int i; float f; } c;
    c.i = u << 16;
    return c.f;
}
__device__ inline unsigned short f2bf(float f) {
    union { __hip_bfloat16 h; unsigned short u; } c;
    c.h = __float2bfloat16(f);
    return c.u;
}

// ---------------- CSR build ----------------

__global__ __launch_bounds__(256) void count_edges(const int* __restrict__ dst, int E,
                                                   int* __restrict__ cnt) {
    int e = blockIdx.x * 256 + threadIdx.x;
    if (e < E) atomicAdd(&cnt[dst[e]], 1);
}

__global__ __launch_bounds__(512) void block_reduce(const int* __restrict__ in, int n,
                                                    int* __restrict__ bsum) {
    __shared__ int s[512];
    int i = blockIdx.x * 512 + threadIdx.x;
    s[threadIdx.x] = (i < n) ? in[i] : 0;
    __syncthreads();
    for (int off = 256; off; off >>= 1) {
        if (threadIdx.x < off) s[threadIdx.x] += s[threadIdx.x + off];
        __syncthreads();
    }
    if (threadIdx.x == 0) bsum[blockIdx.x] = s[0];
}

__global__ __launch_bounds__(512) void scan_bsums(int* bsum, int nb) {
    __shared__ int buf[2][512];
    int t = threadIdx.x;
    int v = (t < nb) ? bsum[t] : 0;
    buf[0][t] = v;
    __syncthreads();
    int src = 0;
    for (int off = 1; off < 512; off <<= 1) {
        int x = buf[src][t];
        if (t >= off) x += buf[src][t - off];
        buf[src ^ 1][t] = x;
        src ^= 1;
        __syncthreads();
    }
    if (t < nb) bsum[t] = buf[src][t] - v;  // exclusive
}

__global__ __launch_bounds__(512) void block_scan_write(const int* __restrict__ cnt,
                                                        const int* __restrict__ bsum, int n,
                                                        int* __restrict__ rowptr) {
    __shared__ int buf[2][512];
    int t = threadIdx.x;
    int i = blockIdx.x * 512 + t;
    int v = (i < n) ? cnt[i] : 0;
    buf[0][t] = v;
    __syncthreads();
    int src = 0;
    for (int off = 1; off < 512; off <<= 1) {
        int x = buf[src][t];
        if (t >= off) x += buf[src][t - off];
        buf[src ^ 1][t] = x;
        src ^= 1;
        __syncthreads();
    }
    int incl = buf[src][t];
    int base = bsum[blockIdx.x];
    if (i < n) rowptr[i] = base + incl - v;
    if (i == n - 1) rowptr[n] = base + incl;
}

__global__ __launch_bounds__(256) void fill_csr(const int* __restrict__ src,
                                                const int* __restrict__ dst, int E,
                                                const int* __restrict__ rowptr,
                                                int* __restrict__ cur, int* __restrict__ col) {
    int e = blockIdx.x * 256 + threadIdx.x;
    if (e < E) {
        int d = dst[e];
        int p = atomicAdd(&cur[d], 1);
        col[rowptr[d] + p] = src[e];
    }
}

__global__ __launch_bounds__(256) void compute_dinv(const int* __restrict__ rowptr, int n,
                                                    float* __restrict__ dinv) {
    int v = blockIdx.x * 256 + threadIdx.x;
    if (v < n) {
        int deg = rowptr[v + 1] - rowptr[v] + 1;  // +1 self loop
        dinv[v] = rsqrtf((float)deg);
    }
}

__global__ __launch_bounds__(64) void graph_bounds(const int* __restrict__ batch, int n, int ng,
                                                   int* __restrict__ gstart) {
    int b = blockIdx.x * 64 + threadIdx.x;
    if (b > ng) return;
    if (b == ng) { gstart[ng] = n; return; }
    int lo = 0, hi = n;
    while (lo < hi) {
        int mid = (lo + hi) >> 1;
        if (batch[mid] < b) lo = mid + 1; else hi = mid;
    }
    gstart[b] = lo;
}

// ---- xs[v] = x[v]*dinv[v] -> bf16 [N][80] (cols 78,79 = 0) ----

__global__ __launch_bounds__(256) void scale_x(const float* __restrict__ x,
                                               const float* __restrict__ dinv,
                                               unsigned short* __restrict__ XS) {
    int idx = blockIdx.x * 256 + threadIdx.x;
    int v = idx / 40, c = idx % 40;
    if (v >= N_NODES) return;
    if (c == 39) {
        *(unsigned int*)(XS + (size_t)v * 80 + 78) = 0u;
        return;
    }
    float dv = dinv[v];
    f32x2 xv = *(const f32x2*)(x + (size_t)v * 78 + c * 2);
    unsigned int pack = ((unsigned int)f2bf(xv.y * dv) << 16) | f2bf(xv.x * dv);
    *(unsigned int*)(XS + (size_t)v * 80 + c * 2) = pack;
}

// ---- aggregation on pre-scaled features: out[v] = dinv[v]*(sum_{u in N(v)} X[u] + X[v]) ----
// X bf16 [N][LD], 16B chunks. NPB nodes per 256-thread block.

template <int LD, int NCH, int NPB>
__global__ __launch_bounds__(256) void agg_sum(const unsigned short* __restrict__ X,
                                               const float* __restrict__ dinv,
                                               const int* __restrict__ rowptr,
                                               const int* __restrict__ col,
                                               unsigned short* __restrict__ out) {
    int tid = threadIdx.x;
    if (tid >= NPB * NCH) return;
    int v = blockIdx.x * NPB + tid / NCH;
    int c = tid % NCH;
    if (v >= N_NODES) return;
    u32x4 xv = *(const u32x4*)(X + (size_t)v * LD + c * 8);
    float a0 = bf2f(xv.x & 0xffffu), a1 = bf2f(xv.x >> 16);
    float a2 = bf2f(xv.y & 0xffffu), a3 = bf2f(xv.y >> 16);
    float a4 = bf2f(xv.z & 0xffffu), a5 = bf2f(xv.z >> 16);
    float a6 = bf2f(xv.w & 0xffffu), a7 = bf2f(xv.w >> 16);
    int r0 = rowptr[v], r1 = rowptr[v + 1];
    for (int e = r0; e < r1; ++e) {
        int u = col[e];
        u32x4 xu = *(const u32x4*)(X + (size_t)u * LD + c * 8);
        a0 += bf2f(xu.x & 0xffffu);
        a1 += bf2f(xu.x >> 16);
        a2 += bf2f(xu.y & 0xffffu);
        a3 += bf2f(xu.y >> 16);
        a4 += bf2f(xu.z & 0xffffu);
        a5 += bf2f(xu.z >> 16);
        a6 += bf2f(xu.w & 0xffffu);
        a7 += bf2f(xu.w >> 16);
    }
    float dv = dinv[v];
    u32x4 o;
    o.x = ((unsigned int)f2bf(a1 * dv) << 16) | f2bf(a0 * dv);
    o.y = ((unsigned int)f2bf(a3 * dv) << 16) | f2bf(a2 * dv);
    o.z = ((unsigned int)f2bf(a5 * dv) << 16) | f2bf(a4 * dv);
    o.w = ((unsigned int)f2bf(a7 * dv) << 16) | f2bf(a6 * dv);
    *(u32x4*)(out + (size_t)v * LD + c * 8) = o;
}

// ------- MFMA node GEMM: Cout = relu(A @ W + bias) * dinv[row], bf16 in/out -------
// mfma_f32_16x16x32_bf16: A row=lane&15, k=8*(lane>>4)+j; B col=lane&15; D col=lane&15,
// row=4*(lane>>4)+r.  W staged in LDS in fragment-linear order.

template <int KREAL, int NREAL, int LDA, int LDC, int NF, int KS>
__global__ __launch_bounds__(256) void gemm_mfma_node(const unsigned short* __restrict__ A,
                                                      const float* __restrict__ W,
                                                      const float* __restrict__ bias,
                                                      const float* __restrict__ dinv,
                                                      unsigned short* __restrict__ Cout, int M) {
    __shared__ unsigned short Bs[NF * KS * 64 * 8];
    int tid = threadIdx.x;
    for (int idx = tid; idx < NF * KS * 64; idx += 256) {
        int l = idx & 63, ks = (idx >> 6) % KS, nf = idx / (64 * KS);
        int k0 = ks * 32 + 8 * (l >> 4);
        int cc = nf * 16 + (l & 15);
        short8v t;
#pragma unroll
        for (int j = 0; j < 8; j++) {
            int k = k0 + j;
            float w = (k < KREAL && cc < NREAL) ? W[(size_t)k * NREAL + cc] : 0.f;
            t[j] = (short)f2bf(w);
        }
        *(short8v*)&Bs[idx * 8] = t;
    }
    __syncthreads();

    int lane = tid & 63, wid = tid >> 6;
    int m0 = blockIdx.x * 128 + wid * 32;
    float biasr[NF];
#pragma unroll
    for (int nf = 0; nf < NF; nf++) {
        int cc = nf * 16 + (lane & 15);
        biasr[nf] = (cc < NREAL) ? bias[cc] : 0.f;
    }
    f32x4 acc[2][NF];
#pragma unroll
    for (int mf = 0; mf < 2; mf++)
#pragma unroll
        for (int nf = 0; nf < NF; nf++) acc[mf][nf] = (f32x4){0.f, 0.f, 0.f, 0.f};

    int ra = min(m0 + (lane & 15), M - 1);
    int rb = min(m0 + 16 + (lane & 15), M - 1);
#pragma unroll
    for (int ks = 0; ks < KS; ks++) {
        int koff = ks * 32 + 8 * (lane >> 4);
        short8v a0 = *(const short8v*)(A + (size_t)ra * LDA + koff);
        short8v a1 = *(const short8v*)(A + (size_t)rb * LDA + koff);
#pragma unroll
        for (int nf = 0; nf < NF; nf++) {
            short8v b = *(const short8v*)&Bs[((nf * KS + ks) * 64 + lane) * 8];
            acc[0][nf] = __builtin_amdgcn_mfma_f32_16x16x32_bf16(a0, b, acc[0][nf], 0, 0, 0);
            acc[1][nf] = __builtin_amdgcn_mfma_f32_16x16x32_bf16(a1, b, acc[1][nf], 0, 0, 0);
        }
    }
    float dr[2][4];
#pragma unroll
    for (int mf = 0; mf < 2; mf++)
#pragma unroll
        for (int r = 0; r < 4; r++) {
            int row = m0 + mf * 16 + 4 * (lane >> 4) + r;
            dr[mf][r] = dinv[min(row, M - 1)];
        }
#pragma unroll
    for (int mf = 0; mf < 2; mf++) {
#pragma unroll
        for (int nf = 0; nf < NF; nf++) {
            int cc = nf * 16 + (lane & 15);
#pragma unroll
            for (int r = 0; r < 4; r++) {
                int row = m0 + mf * 16 + 4 * (lane >> 4) + r;
                float v = fmaxf(acc[mf][nf][r] + biasr[nf], 0.f) * dr[mf][r];
                unsigned short o = (cc < NREAL) ? f2bf(v) : (unsigned short)0;
                if (row < M) Cout[(size_t)row * LDC + cc] = o;
            }
        }
    }
}

// ------- layer-3 GEMM fused with per-graph segment-max; grid (5 col-blocks, 512 graphs) ----
// A bf16 [N][160] (K=156 padded), W3 f32 [156][312], out g3 f32 [512][312]

__global__ __launch_bounds__(256) void seg_gemm_max(const unsigned short* __restrict__ A,
                                                    const float* __restrict__ W3,
                                                    const float* __restrict__ b3,
                                                    const int* __restrict__ gstart,
                                                    float* __restrict__ g3) {
    __shared__ unsigned short Bs[4 * 5 * 64 * 8];  // 20 KB
    __shared__ float wmax[4][64];
    int g = blockIdx.y;
    int c0 = blockIdx.x * 64;
    int r0 = gstart[g], r1 = gstart[g + 1];
    int tid = threadIdx.x, lane = tid & 63, wid = tid >> 6;

    for (int idx = tid; idx < 1280; idx += 256) {
        int l = idx & 63, ks = (idx >> 6) % 5, nf = idx / 320;
        int k0 = ks * 32 + 8 * (l >> 4);
        int cc = c0 + nf * 16 + (l & 15);
        short8v t;
#pragma unroll
        for (int j = 0; j < 8; j++) {
            int k = k0 + j;
            float w = (k < 156 && cc < 312) ? W3[(size_t)k * 312 + cc] : 0.f;
            t[j] = (short)f2bf(w);
        }
        *(short8v*)&Bs[idx * 8] = t;
    }
    __syncthreads();

    float biasr[4], cmax[4];
#pragma unroll
    for (int nf = 0; nf < 4; nf++) {
        int cc = c0 + nf * 16 + (lane & 15);
        biasr[nf] = (cc < 312) ? b3[cc] : 0.f;
        cmax[nf] = 0.f;
    }

    for (int mt = r0 + wid * 32; mt < r1; mt += 128) {
        f32x4 acc[2][4];
#pragma unroll
        for (int mf = 0; mf < 2; mf++)
#pragma unroll
            for (int nf = 0; nf < 4; nf++) acc[mf][nf] = (f32x4){0.f, 0.f, 0.f, 0.f};
        int ra = min(mt + (lane & 15), N_NODES - 1);
        int rb = min(mt + 16 + (lane & 15), N_NODES - 1);
#pragma unroll
        for (int ks = 0; ks < 5; ks++) {
            int koff = ks * 32 + 8 * (lane >> 4);
            short8v a0 = *(const short8v*)(A + (size_t)ra * 160 + koff);
            short8v a1 = *(const short8v*)(A + (size_t)rb * 160 + koff);
#pragma unroll
            for (int nf = 0; nf < 4; nf++) {
                short8v b = *(const short8v*)&Bs[((nf * 5 + ks) * 64 + lane) * 8];
                acc[0][nf] = __builtin_amdgcn_mfma_f32_16x16x32_bf16(a0, b, acc[0][nf], 0, 0, 0);
                acc[1][nf] = __builtin_amdgcn_mfma_f32_16x16x32_bf16(a1, b, acc[1][nf], 0, 0, 0);
            }
        }
#pragma unroll
        for (int mf = 0; mf < 2; mf++) {
#pragma unroll
            for (int nf = 0; nf < 4; nf++) {
#pragma unroll
                for (int r = 0; r < 4; r++) {
                    int row = mt + mf * 16 + 4 * (lane >> 4) + r;
                    float v = fmaxf(acc[mf][nf][r] + biasr[nf], 0.f);
                    if (row < r1) cmax[nf] = fmaxf(cmax[nf], v);
                }
            }
        }
    }
#pragma unroll
    for (int nf = 0; nf < 4; nf++) {
        float m = cmax[nf];
        m = fmaxf(m, __shfl_xor(m, 16));
        m = fmaxf(m, __shfl_xor(m, 32));
        if (lane < 16) wmax[wid][nf * 16 + lane] = m;
    }
    __syncthreads();
    if (tid < 64) {
        float m = fmaxf(fmaxf(wmax[0][tid], wmax[1][tid]), fmaxf(wmax[2][tid], wmax[3][tid]));
        int cc = c0 + tid;
        if (cc < 312) g3[(size_t)g * 312 + cc] = m;
    }
}

// ---------------- head GEMMs: split-K, atomicAdd into bias-initialized C ----------------

__global__ __launch_bounds__(256) void init_bias(float* __restrict__ C,
                                                 const float* __restrict__ bias, int M, int N,
                                                 int ldc) {
    int idx = blockIdx.x * 256 + threadIdx.x;
    if (idx < M * N) C[(size_t)(idx / N) * ldc + (idx % N)] = bias[idx % N];
}

template <int RELUA>
__global__ __launch_bounds__(256) void gemm_splitk(const float* __restrict__ A,
                                                   const float* __restrict__ B,
                                                   float* __restrict__ C, int M, int N, int K,
                                                   int ldc, int Kc) {
    __shared__ float As[16][17];
    __shared__ float Bs[16][64];
    int bx = blockIdx.x, by = blockIdx.y, bz = blockIdx.z;
    int tid = threadIdx.x;
    int lane = tid & 63, wy = tid >> 6;
    int n0 = bx * 64, m0 = by * 16;
    int k0 = bz * Kc, k1 = min(K, k0 + Kc);
    float acc[4] = {0.f, 0.f, 0.f, 0.f};
    for (int kt = k0; kt < k1; kt += 16) {
        {
            int r = tid >> 4, kk = tid & 15;
            int gm = m0 + r, gk = kt + kk;
            float v = (gk < k1 && gm < M) ? A[(size_t)gm * K + gk] : 0.f;
            if (RELUA) v = fmaxf(v, 0.f);
            As[kk][r] = v;
        }
#pragma unroll
        for (int l = 0; l < 4; l++) {
            int kk = wy + l * 4;
            int gk = kt + kk, gn = n0 + lane;
            Bs[kk][lane] = (gk < k1 && gn < N) ? B[(size_t)gk * N + gn] : 0.f;
        }
        __syncthreads();
#pragma unroll
        for (int kk = 0; kk < 16; kk++) {
            float b = Bs[kk][lane];
#pragma unroll
            for (int r = 0; r < 4; r++) acc[r] += As[kk][wy * 4 + r] * b;
        }
        __syncthreads();
    }
    int gn = n0 + lane;
    if (gn < N) {
#pragma unroll
        for (int r = 0; r < 4; r++) {
            int gm = m0 + wy * 4 + r;
            if (gm < M) atomicAdd(&C[(size_t)gm * ldc + gn], acc[r]);
        }
    }
}

// ---------------- conv head: c[n,o,w] = sum_t sum_k emb[t,w+k] * A[n,t,o,k] + convb[o] ----

__global__ __launch_bounds__(256) void conv_head(const int* __restrict__ target,
                                                 const float* __restrict__ emb,
                                                 const float* __restrict__ convw,
                                                 const float* __restrict__ convb,
                                                 float* __restrict__ c) {
    __shared__ float A[26 * 256];
    __shared__ float emb_s[26 * 128];
    __shared__ int tg[1000];
    int n = blockIdx.x, tid = threadIdx.x;
    for (int i = tid; i < 26 * 256; i += 256) A[i] = 0.f;
    for (int i = tid; i < 26 * 128; i += 256) emb_s[i] = emb[i];
    for (int i = tid; i < 1000; i += 256) tg[i] = target[n * 1000 + i];
    __syncthreads();
    int o = tid >> 3, k = tid & 7;
    const float* cw = convw + o * 8000 + k;
    for (int i = 0; i < 1000; i++) {
        int t = tg[i];
        A[t * 256 + tid] += cw[i * 8];
    }
    __syncthreads();
    for (int idx = tid; idx < 32 * 121; idx += 256) {
        int oo = idx / 121, w = idx % 121;
        float acc = convb[oo];
#pragma unroll
        for (int t = 0; t < 26; t++) {
            const float* er = &emb_s[t * 128 + w];
            const float* ar = &A[t * 256 + oo * 8];
#pragma unroll
            for (int kk = 0; kk < 8; kk++) acc += er[kk] * ar[kk];
        }
        c[(size_t)n * 3872 + idx] = acc;
    }
}

// ---------------- final N=1 matvec (relu on load) ----------------

__global__ __launch_bounds__(256) void rowdot(const float* __restrict__ f2,
                                              const float* __restrict__ Wo,
                                              const float* __restrict__ bo,
                                              float* __restrict__ out, int M, int K) {
    int row = blockIdx.x * 4 + (threadIdx.x >> 6);
    int lane = threadIdx.x & 63;
    if (row >= M) return;
    float acc = 0.f;
    for (int k = lane; k < K; k += 64) acc += fmaxf(f2[(size_t)row * K + k], 0.f) * Wo[k];
    for (int off = 32; off; off >>= 1) acc += __shfl_down(acc, off);
    if (lane == 0) out[row] = acc + bo[0];
}

// ---------------- launch ----------------

extern "C" void kernel_launch(void* const* d_in, const int* in_sizes, int n_in, void* d_out,
                              int out_size, void* d_ws, size_t ws_size, hipStream_t stream) {
    const float* x = (const float*)d_in[0];
    const int* ei = (const int*)d_in[1];
    const int* batch = (const int*)d_in[2];
    const int* target = (const int*)d_in[3];
    const float* W1 = (const float*)d_in[4];
    const float* b1 = (const float*)d_in[5];
    const float* W2 = (const float*)d_in[6];
    const float* b2 = (const float*)d_in[7];
    const float* W3 = (const float*)d_in[8];
    const float* b3 = (const float*)d_in[9];
    const float* Wg1 = (const float*)d_in[10];
    const float* bg1 = (const float*)d_in[11];
    const float* Wg2 = (const float*)d_in[12];
    const float* bg2 = (const float*)d_in[13];
    const float* emb = (const float*)d_in[14];
    const float* convw = (const float*)d_in[15];
    const float* convb = (const float*)d_in[16];
    const float* Wxt = (const float*)d_in[17];
    const float* bxt = (const float*)d_in[18];
    const float* Wf1 = (const float*)d_in[19];
    const float* bf1 = (const float*)d_in[20];
    const float* Wf2 = (const float*)d_in[21];
    const float* bf2 = (const float*)d_in[22];
    const float* Wo = (const float*)d_in[23];
    const float* bo = (const float*)d_in[24];
    float* out = (float*)d_out;

    const int N = N_NODES, E = N_EDGES;
    const int NB = (N + 511) / 512;

    char* ws = (char*)d_ws;
    size_t off = 0;
    auto alloc = [&](size_t bytes) -> char* {
        char* p = ws + off;
        off = (off + bytes + 255) & ~(size_t)255;
        return p;
    };
    int* cnt = (int*)alloc((size_t)N * 4);
    int* rowptr = (int*)alloc((size_t)(N + 1) * 4);
    int* bsum = (int*)alloc(512 * 4);
    int* col = (int*)alloc((size_t)E * 4);
    float* dinv = (float*)alloc((size_t)N * 4);
    int* gstart = (int*)alloc((N_GRAPHS + 1) * 4);
    float* g3 = (float*)alloc((size_t)N_GRAPHS * 312 * 4);
    float* gg = (float*)alloc((size_t)N_GRAPHS * 1024 * 4);
    float* cbuf = (float*)alloc((size_t)N_GRAPHS * 3872 * 4);
    float* xc = (float*)alloc((size_t)N_GRAPHS * 256 * 4);
    float* f1 = (float*)alloc((size_t)N_GRAPHS * 1024 * 4);
    float* f2 = (float*)alloc((size_t)N_GRAPHS * 512 * 4);
    unsigned short* U = (unsigned short*)alloc((size_t)N * 160 * 2 + 512);
    unsigned short* P160 = (unsigned short*)alloc((size_t)N * 160 * 2 + 512);
    unsigned short* H1 = U + (size_t)N * 80;  // [N,80] second half of U

    const int* srcp = ei;
    const int* dstp = ei + E;

    // CSR + norm
    hipMemsetAsync(cnt, 0, (size_t)N * 4, stream);
    count_edges<<<(E + 255) / 256, 256, 0, stream>>>(dstp, E, cnt);
    block_reduce<<<NB, 512, 0, stream>>>(cnt, N, bsum);
    scan_bsums<<<1, 512, 0, stream>>>(bsum, NB);
    block_scan_write<<<NB, 512, 0, stream>>>(cnt, bsum, N, rowptr);
    hipMemsetAsync(cnt, 0, (size_t)N * 4, stream);
    fill_csr<<<(E + 255) / 256, 256, 0, stream>>>(srcp, dstp, E, rowptr, cnt, col);
    compute_dinv<<<(N + 255) / 256, 256, 0, stream>>>(rowptr, N, dinv);
    graph_bounds<<<(N_GRAPHS + 1 + 63) / 64, 64, 0, stream>>>(batch, N, N_GRAPHS, gstart);

    // bias-init split-K outputs
    init_bias<<<(512 * 1024 + 255) / 256, 256, 0, stream>>>(gg, bg1, 512, 1024, 1024);
    init_bias<<<(512 * 128 + 255) / 256, 256, 0, stream>>>(xc, bg2, 512, 128, 256);
    init_bias<<<(512 * 128 + 255) / 256, 256, 0, stream>>>(xc + 128, bxt, 512, 128, 256);
    init_bias<<<(512 * 1024 + 255) / 256, 256, 0, stream>>>(f1, bf1, 512, 1024, 1024);
    init_bias<<<(512 * 512 + 255) / 256, 256, 0, stream>>>(f2, bf2, 512, 512, 512);

    const int MB = (N + 127) / 128;  // 1563

    // layer 1: XS = x*dinv (P160); A1 = aggsum(XS) (U80); h1' = relu(A1@W1+b1)*dinv (H1)
    scale_x<<<(N * 40 + 255) / 256, 256, 0, stream>>>(x, dinv, P160);
    agg_sum<80, 10, 25><<<(N + 24) / 25, 256, 0, stream>>>(P160, dinv, rowptr, col, U);
    gemm_mfma_node<78, 78, 80, 80, 5, 3><<<MB, 256, 0, stream>>>(U, W1, b1, dinv, H1, N);
    // layer 2: A2 = aggsum(h1') (P160[:,:80]); h2' = relu(A2@W2+b2)*dinv (U as [N,160])
    agg_sum<80, 10, 25><<<(N + 24) / 25, 256, 0, stream>>>(H1, dinv, rowptr, col, P160);
    gemm_mfma_node<78, 156, 80, 160, 10, 3><<<MB, 256, 0, stream>>>(P160, W2, b2, dinv, U, N);
    // layer 3: A3 = aggsum(h2') (P160 [N,160]); fused GEMM + per-graph segment max
    agg_sum<160, 20, 12><<<(N + 11) / 12, 256, 0, stream>>>(U, dinv, rowptr, col, P160);
    seg_gemm_max<<<dim3(5, N_GRAPHS), 256, 0, stream>>>(P160, W3, b3, gstart, g3);

    // graph head
    gemm_splitk<0><<<dim3(16, 32, 2), 256, 0, stream>>>(g3, Wg1, gg, 512, 1024, 312, 1024, 160);
    gemm_splitk<1><<<dim3(2, 32, 8), 256, 0, stream>>>(gg, Wg2, xc, 512, 128, 1024, 256, 128);

    // conv head
    conv_head<<<N_GRAPHS, 256, 0, stream>>>(target, emb, convw, convb, cbuf);
    gemm_splitk<0><<<dim3(2, 32, 16), 256, 0, stream>>>(cbuf, Wxt, xc + 128, 512, 128, 3872, 256, 256);

    // final MLP
    gemm_splitk<0><<<dim3(16, 32, 2), 256, 0, stream>>>(xc, Wf1, f1, 512, 1024, 256, 1024, 128);
    gemm_splitk<1><<<dim3(8, 32, 8), 256, 0, stream>>>(f1, Wf2, f2, 512, 512, 1024, 512, 128);
    rowdot<<<(N_GRAPHS + 3) / 4, 256, 0, stream>>>(f2, Wo, bo, out, N_GRAPHS, 512);
}